// Round 5
// baseline (320.213 us; speedup 1.0000x reference)
//
#include <hip/hip_runtime.h>
#include <hip/hip_bf16.h>
#include <hip/hip_fp16.h>

// ---------------------------------------------------------------------------
// FakeQuantLinear (Q4_K_M fake-quant + GEMM): out = x @ fq(W)^T + bias
// R11 == R10 resubmitted verbatim (R4's bench died with "MI355X container
//      failed twice" — infra failure, no kernel verdict, no counters).
// R10: abandon counted-vmcnt scheduling (R7/R8/R9 all landed -17..-23% vs R6,
//      matching m196's "coarse phase-split without exact fine interleave
//      HURTS -7..-27%"). Keep R6's proven skeleton (BK=64 single-buffer,
//      syncthreads drain, 2 blocks/CU inter-block overlap) and switch the
//      instruction class: 16x16x32 -> 32x32x16 bf16 MFMA (+15% pipe rate
//      2382 vs 2075 TF ubench, half the instructions, same LDS traffic).
//      LDS layout [k16-group][row][2x16B]: each operand read's 64 lanes cover
//      a contiguous 1024B region bijectively -> 2 lanes/bank = free, no
//      swizzle. Staging stays linear (dest = j*4096 + tid*16).
// ---------------------------------------------------------------------------

typedef __attribute__((ext_vector_type(8))) short bf16x8;    // 8 bf16 = 4 VGPRs
typedef __attribute__((ext_vector_type(8))) unsigned short ushort8;
typedef __attribute__((ext_vector_type(16))) float f32x16;   // 32x32 MFMA acc

__device__ __forceinline__ unsigned short f2bf(float f) {
  unsigned int u = __float_as_uint(f);
  u += 0x7fffu + ((u >> 16) & 1u);
  return (unsigned short)(u >> 16);
}

// ---------------------------------------------------------------------------
// Fused prep kernel (unchanged from R4/R6).
// ---------------------------------------------------------------------------
__global__ __launch_bounds__(256) void prep_kernel(
    const float* __restrict__ x, unsigned short* __restrict__ xb,
    const float* __restrict__ w, unsigned short* __restrict__ wq,
    int castBlocks) {
  if ((int)blockIdx.x < castBlocks) {
    const size_t i = ((size_t)blockIdx.x * 256 + threadIdx.x) * 8;
    const float4 a = *(const float4*)(x + i);
    const float4 b = *(const float4*)(x + i + 4);
    ushort8 o = {f2bf(a.x), f2bf(a.y), f2bf(a.z), f2bf(a.w),
                 f2bf(b.x), f2bf(b.y), f2bf(b.z), f2bf(b.w)};
    *(ushort8*)(xb + i) = o;
    return;
  }
  const int qb   = blockIdx.x - castBlocks;
  const int lane = threadIdx.x & 63;
  const int wv   = threadIdx.x >> 6;
  const size_t base = (((size_t)qb * 4 + wv) * 256) + (size_t)lane * 4;
  const float4 v = *(const float4*)(w + base);

  float mn = fminf(fminf(v.x, v.y), fminf(v.z, v.w));
  float mx = fmaxf(fmaxf(v.x, v.y), fmaxf(v.z, v.w));
#pragma unroll
  for (int off = 1; off <= 4; off <<= 1) {
    mn = fminf(mn, __shfl_xor(mn, off));
    mx = fmaxf(mx, __shfl_xor(mx, off));
  }
  const float sub_min = fminf(mn, 0.0f);
  const float sub_max = fmaxf(mx, 0.0f);
  const float scale_raw = fmaxf(sub_max - sub_min, 1e-8f) / 15.0f;

  float smn = scale_raw, smx = scale_raw, supermin = sub_min;
#pragma unroll
  for (int off = 8; off <= 32; off <<= 1) {
    smn = fminf(smn, __shfl_xor(smn, off));
    smx = fmaxf(smx, __shfl_xor(smx, off));
    supermin = fminf(supermin, __shfl_xor(supermin, off));
  }
  const float s_range = fmaxf(smx - smn, 1e-8f);
  float s_int = rintf((scale_raw - smn) / s_range * 63.0f);
  s_int = fminf(fmaxf(s_int, 0.0f), 63.0f);
  float scale = s_int / 63.0f * s_range + smn;
  scale = fmaxf(scale, 1e-8f);
  const float inv_scale = 1.0f / scale;

  const float sm  = __half2float(__float2half(supermin));
  const float adj = sub_min - sm;

  float e[4] = {v.x, v.y, v.z, v.w};
  ushort4 o;
  unsigned short* op = (unsigned short*)&o;
#pragma unroll
  for (int k = 0; k < 4; ++k) {
    const float t = (e[k] - sm) - adj;
    float qv = rintf(t * inv_scale);
    qv = fminf(fmaxf(qv, 0.0f), 15.0f);
    op[k] = f2bf((qv * scale + adj) + sm);
  }
  *(ushort4*)(wq + base) = o;
}

// ---------------------------------------------------------------------------
// bf16 MFMA GEMM, C[m,n] = sum_k A[m,k]*B[n,k] + bias[n]
// Block tile 256x128, BK=64, 256 thr = 4 waves (2x2), wave tile 128x64.
// MFMA 32x32x16: per wave-step 4(i) x 2(j) x 4(t) = 32 MFMAs, acc f32x16[4][2].
// LDS 48 KiB (2 blocks/CU). Layout: off(row,k) = (k>>4)*ROWS*32B + row*32B
// + (k&15)*2B. Operand reads: lane -> (row = base + lane&31, 16B half =
// lane>>5) => 64 lanes cover one contiguous 1024B region => conflict-free.
// Staging: issue j dest = j*4096B + tid*16B == (row=tid>>1, k8half=tid&1).
// ---------------------------------------------------------------------------
#define BM 256
#define BN 128
#define BK 64

__device__ __forceinline__ void async_cp16(void* lds, const void* g) {
  __builtin_amdgcn_global_load_lds(
      (__attribute__((address_space(1))) void*)(void*)g,
      (__attribute__((address_space(3))) void*)lds, 16, 0, 0);
}

__global__ __launch_bounds__(256, 2) void gemm_bt_kernel(
    const unsigned short* __restrict__ A,   // [M][K] bf16 bits
    const unsigned short* __restrict__ B,   // [N][K] bf16 bits (fq weight)
    const float* __restrict__ bias,         // [N]
    float* __restrict__ C,                  // [M][N] f32
    int M, int N, int K) {
  __shared__ unsigned short lds_a[BM * BK];   // 32 KiB: 4 groups x 8192 B
  __shared__ unsigned short lds_b[BN * BK];   // 16 KiB: 4 groups x 4096 B

  const int tid  = threadIdx.x;
  const int lane = tid & 63;
  const int wv   = tid >> 6;
  const int wm   = wv >> 1;          // wave row (128 rows each)
  const int wn   = wv & 1;           // wave col (64 cols each)
  const int bx   = blockIdx.x;       // N tile (128)
  const int by   = blockIdx.y;       // M tile (256)

  // --- staging: thread t -> row t>>1, k8-half t&1 (16 B each).
  // A issue j (j=0..7): k16-group j>>1, row-half j&1; dest = j*4096B + tid*16B.
  // B issue j (j=0..3): k16-group j;                  dest = j*4096B + tid*16B.
  const int srow  = tid >> 1;                      // 0..127
  const int skoff = (tid & 1) * 8;                 // ushort offset (k8-half)
  const unsigned short* gA0 = A + (size_t)(by * BM + srow) * K + skoff;
  const unsigned short* gA1 = gA0 + (size_t)128 * K;
  const unsigned short* gB0 = B + (size_t)(bx * BN + srow) * K + skoff;

  // --- fragment reads: row = base + (lane&31), 16B-half = lane>>5.
  const int r32   = lane & 31;
  const int khalf = (lane >> 5) * 16;              // byte offset within 32B row
  const int abase = (wm * 128 + r32) * 32 + khalf; // bytes within a k16-group
  const int bbase = (wn * 64  + r32) * 32 + khalf;

  f32x16 acc[4][2] = {};   // 128 f32 accumulators (AGPR)

  for (int k0 = 0; k0 < K; k0 += BK) {
#pragma unroll
    for (int j = 0; j < 8; ++j) {
      const unsigned short* src = (j & 1) ? gA1 : gA0;
      async_cp16((char*)lds_a + j * 4096 + tid * 16, src + k0 + (j >> 1) * 16);
    }
#pragma unroll
    for (int j = 0; j < 4; ++j)
      async_cp16((char*)lds_b + j * 4096 + tid * 16, gB0 + k0 + j * 16);
    __syncthreads();   // drain staging

#pragma unroll
    for (int h = 0; h < 2; ++h) {
      bf16x8 af[4][2], bfr[2][2];
#pragma unroll
      for (int t2 = 0; t2 < 2; ++t2) {
        const int t = 2 * h + t2;
#pragma unroll
        for (int i = 0; i < 4; ++i)
          af[i][t2] = *(const bf16x8*)((const char*)lds_a + t * 8192 + abase + i * 1024);
#pragma unroll
        for (int j = 0; j < 2; ++j)
          bfr[j][t2] = *(const bf16x8*)((const char*)lds_b + t * 4096 + bbase + j * 1024);
      }
#pragma unroll
      for (int i = 0; i < 4; ++i)
#pragma unroll
        for (int j = 0; j < 2; ++j)
#pragma unroll
          for (int t2 = 0; t2 < 2; ++t2)
            acc[i][j] = __builtin_amdgcn_mfma_f32_32x32x16_bf16(
                af[i][t2], bfr[j][t2], acc[i][j], 0, 0, 0);
    }
    __syncthreads();   // protect LDS before next stage
  }

  // Epilogue. 32x32 C/D layout: col = lane&31, row = (r&3) + 8*(r>>2) + 4*(lane>>5)
  const int rbase = by * BM + wm * 128 + 4 * (lane >> 5);
  const int cbase = bx * BN + wn * 64 + r32;
#pragma unroll
  for (int j = 0; j < 2; ++j) {
    const int c = cbase + j * 32;
    const float bv = bias[c];
#pragma unroll
    for (int i = 0; i < 4; ++i) {
#pragma unroll
      for (int r = 0; r < 16; ++r) {
        const int row = rbase + i * 32 + (r & 3) + 8 * (r >> 2);
        C[(size_t)row * N + c] = acc[i][j][r] + bv;
      }
    }
  }
}

// ---------------------------------------------------------------------------
extern "C" void kernel_launch(void* const* d_in, const int* in_sizes, int n_in,
                              void* d_out, int out_size, void* d_ws, size_t ws_size,
                              hipStream_t stream) {
  const float* x    = (const float*)d_in[0];
  const float* w    = (const float*)d_in[1];
  const float* bias = (const float*)d_in[2];
  float* out = (float*)d_out;

  const long long xn = in_sizes[0];   // M*K
  const long long wn = in_sizes[1];   // N*K
  const int N = in_sizes[2];
  const int K = (int)(wn / N);
  const int M = (int)(xn / K);

  unsigned short* xb = (unsigned short*)d_ws;
  unsigned short* wb = xb + (size_t)M * K;

  const int castBlocks  = (int)(xn / (256 * 8));    // 8 elems/thread
  const int quantBlocks = (int)(wn / (256 * 4));    // 1024 elems/block
  prep_kernel<<<castBlocks + quantBlocks, 256, 0, stream>>>(x, xb, w, wb,
                                                            castBlocks);
  gemm_bt_kernel<<<dim3(N / BN, M / BM), 256, 0, stream>>>(xb, wb, bias, out,
                                                           M, N, K);
}